// Round 16
// baseline (1155.498 us; speedup 1.0000x reference)
//
#include <hip/hip_runtime.h>
#include <cstddef>
#include <cstdint>

#define HW96 9216
#define FRAME (64 * 9216)

typedef unsigned short ushort_t;
typedef __attribute__((ext_vector_type(8))) short bf16x8;
typedef __attribute__((ext_vector_type(4))) float f32x4;
typedef __attribute__((ext_vector_type(4))) unsigned u32x4;
typedef __attribute__((ext_vector_type(8))) ushort_t u16x8;
typedef __attribute__((ext_vector_type(4))) ushort_t u16x4;

__device__ __forceinline__ void split16(float v, ushort_t& h, ushort_t& l) {
    unsigned u = __float_as_uint(v);
    h = (ushort_t)(u >> 16);
    float rem = v - __uint_as_float(u & 0xFFFF0000u);
    unsigned r = __float_as_uint(rem);
    l = (ushort_t)((r + 0x7FFFu + ((r >> 16) & 1u)) >> 16);
}
__device__ __forceinline__ ushort_t bf16rnd(float v) {
    unsigned u = __float_as_uint(v);
    return (ushort_t)((u + 0x7FFFu + ((u >> 16) & 1u)) >> 16);
}
__device__ __forceinline__ float bfh(ushort_t h) {
    return __uint_as_float(((unsigned)h) << 16);
}

// ---------------------------------------------------------------------------
// MFMA A-fragment prepack (16x16x32) with bf16 hi/lo split.
// mode 0 (3x3 conv): layout [hl][t][cc][ot][lane][j]; K = cin chunks of 32.
// mode 1 (dconv):    layout [hl][cc][ot][lane][j]; K = g*72 + tap*8 + c.
// mode 2 (1x1 conv): layout [hl][cc][ot][lane][j]; K = cin chunks of 32.
// ---------------------------------------------------------------------------
struct FragJob { const float* src; ushort_t* dst; int O, I, OT, KC, mode; };
struct FragJobs { FragJob j[15]; };

__global__ __launch_bounds__(256) void frag_all_k(FragJobs jobs) {
    const FragJob& J = jobs.j[blockIdx.y];
    int idx = blockIdx.x * 256 + threadIdx.x;
    int total = ((J.mode == 0) ? 9 : 1) * J.KC * J.OT * 512;
    if (idx >= total) return;
    int jj = idx & 7;
    int lane = (idx >> 3) & 63;
    int rem = idx >> 9;
    int ot = rem % J.OT;
    rem /= J.OT;
    int cc = rem % J.KC;
    int t = rem / J.KC;
    int o = ot * 16 + (lane & 15);
    float wv = 0.f;
    if (J.mode == 0) {
        int ci = cc * 32 + (lane >> 4) * 8 + jj;
        if (o < J.O && ci < J.I) wv = J.src[(o * J.I + ci) * 9 + t];
    } else if (J.mode == 1) {
        int K = cc * 32 + (lane >> 4) * 8 + jj;
        int g = K / 72, r2 = K % 72;
        int tap = r2 >> 3, c = r2 & 7;
        int ci = g * 8 + c;
        if (o < J.O && ci < J.I) wv = J.src[(o * J.I + ci) * 9 + tap];
    } else {  // mode 2: 1x1
        int ci = cc * 32 + (lane >> 4) * 8 + jj;
        if (o < J.O && ci < J.I) wv = J.src[o * J.I + ci];
    }
    ushort_t h, l;
    split16(wv, h, l);
    J.dst[idx] = h;
    J.dst[total + idx] = l;
}

// ---------------------------------------------------------------------------
// Transposing pack: planar fp32 -> interleaved bf16-hi shadow only.
// ---------------------------------------------------------------------------
__global__ __launch_bounds__(256) void pack_tr_k(const float* __restrict__ src,
                                                 ushort_t* __restrict__ dsth) {
    const int t = blockIdx.y;
    const int px0 = blockIdx.x * 64;
    __shared__ ushort_t tile[64 * 65];
    const float* s = src + (size_t)t * FRAME;
    ushort_t* dh = dsth + (size_t)t * FRAME;
#pragma unroll
    for (int it = 0; it < 16; ++it) {
        int e = it * 256 + threadIdx.x;
        int p = e & 63, ch = e >> 6;
        tile[ch * 65 + p] = bf16rnd(s[(size_t)ch * HW96 + px0 + p]);
    }
    __syncthreads();
#pragma unroll
    for (int it = 0; it < 16; ++it) {
        int e = it * 256 + threadIdx.x;
        int ch = e & 63, p = e >> 6;
        dh[(size_t)(px0 + p) * 64 + ch] = tile[ch * 65 + p];
    }
}

// ---------------------------------------------------------------------------
// Hi-only bf16 MFMA 3x3 conv (offset/mask path: ow1/ow2/ow3).
// Sources bf16-hi interleaved; 1 u16x8/job staging; H-only LDS; 1 MFMA/step.
// ---------------------------------------------------------------------------
__global__ __launch_bounds__(128, 3) void convh_k(
    const ushort_t* __restrict__ s0, const ushort_t* __restrict__ s1,
    const ushort_t* __restrict__ s2, int b0, int b1, int b2, int nsrc,
    const ushort_t* __restrict__ wfrag, int KCfull,
    const float* __restrict__ bias, ushort_t* __restrict__ outhi, int act) {
    const int tid = threadIdx.x;
    const int lane = tid & 63;
    const int w = tid >> 6;
    const int h = blockIdx.x & 1;
    const int bseg = blockIdx.x >> 1;
    const int ot = h * 2 + w;
    const int xb = (bseg % 6) * 16;
    const int y = bseg / 6;
    const int n = lane & 15;
    const int quad = lane >> 4;

    __shared__ __align__(16) ushort_t ldsH[3 * 18 * 72];

    int jst[4], jok[4], joff[4], jbase[4];
#pragma unroll
    for (int i = 0; i < 4; ++i) {
        int e = tid + i * 128;
        int rc = e >> 3, cg = e & 7;
        int r = rc / 18, col = rc - r * 18;
        int gy = y - 1 + r, gx = xb - 1 + col;
        jst[i] = (e < 432);
        jok[i] = jst[i] && ((unsigned)gy < 96u) && ((unsigned)gx < 96u);
        joff[i] = (gy * 96 + gx) * 64 + cg * 8;
        jbase[i] = rc * 72 + cg * 8;
    }

    f32x4 acc0, acc1;
#pragma unroll
    for (int r = 0; r < 4; ++r) { acc0[r] = 0.f; acc1[r] = 0.f; }

    for (int j = 0; j < nsrc; ++j) {
        const ushort_t* sv = (j == 0) ? s0 : (j == 1 ? s1 : s2);
        const int base = (j == 0) ? b0 : (j == 1 ? b1 : b2);
        __syncthreads();
#pragma unroll
        for (int i = 0; i < 4; ++i) {
            if (jst[i]) {
                u16x8 a;
                if (jok[i]) {
                    a = *(const u16x8*)(sv + joff[i]);
                } else {
#pragma unroll
                    for (int q = 0; q < 8; ++q) a[q] = 0;
                }
                *(u16x8*)(ldsH + jbase[i]) = a;
            }
        }
        __syncthreads();
        bf16x8 pAh[5], pBh[5];
#pragma unroll
        for (int s = 0; s < 23; ++s) {
            if (s >= 5) {  // consume BEFORE refilling the slot
                const int u = s - 5;
                const bf16x8 Ah = pAh[u % 5];
                const bf16x8 Bh = pBh[u % 5];
                if (u & 1)
                    acc1 = __builtin_amdgcn_mfma_f32_16x16x32_bf16(Ah, Bh, acc1, 0, 0, 0);
                else
                    acc0 = __builtin_amdgcn_mfma_f32_16x16x32_bf16(Ah, Bh, acc0, 0, 0, 0);
            }
            if (s < 18) {
                const int t = s >> 1, cc2 = s & 1;
                const int ky = t / 3, kx = t % 3;
                const int ccor = base + cc2;
                const ushort_t* ab =
                    wfrag + (((size_t)(t * KCfull + ccor) * 4 + ot) * 64 + lane) * 8;
                pAh[s % 5] = *(const bf16x8*)ab;
                const int lb = (ky * 18 + n + kx) * 72 + cc2 * 32 + quad * 8;
                pBh[s % 5] = *(const bf16x8*)(ldsH + lb);
            }
        }
    }

    const int px = y * 96 + xb + n;
    u16x4 hi4;
#pragma unroll
    for (int r = 0; r < 4; ++r) {
        int cout = ot * 16 + quad * 4 + r;
        float v = acc0[r] + acc1[r] + bias[cout];
        if (act) v = (v >= 0.f) ? v : 0.1f * v;
        hi4[r] = bf16rnd(v);
    }
    *(u16x4*)(outhi + (size_t)px * 64 + ot * 16 + quad * 4) = hi4;
}

// ---------------------------------------------------------------------------
// Feature-path hi-only bf16 MFMA 3x3 conv (bw1/bw2).
// dslot stages D = bf16(sum of npacc pacc partials + dbias); bw2 epilogue
// adds addn pacc partials + abias (fp32 vector loads). 1 MFMA/K-step.
// ---------------------------------------------------------------------------
__global__ __launch_bounds__(128, 3) void convb_k(
    const ushort_t* __restrict__ s0, const ushort_t* __restrict__ s1,
    int nsrc, int dslot, const float* __restrict__ dpacc, int npacc,
    const float* __restrict__ ddbias, const ushort_t* __restrict__ wfrag,
    int KCfull, const float* __restrict__ bias, int addn,
    const float* __restrict__ abias, ushort_t* __restrict__ outhi, int act) {
    const int tid = threadIdx.x;
    const int lane = tid & 63;
    const int w = tid >> 6;
    const int h = blockIdx.x & 1;
    const int bseg = blockIdx.x >> 1;
    const int ot = h * 2 + w;
    const int xb = (bseg % 6) * 16;
    const int y = bseg / 6;
    const int n = lane & 15;
    const int quad = lane >> 4;

    __shared__ __align__(16) ushort_t ldsH[3 * 18 * 72];

    int jst[4], jok[4], joff[4], jbase[4];
#pragma unroll
    for (int i = 0; i < 4; ++i) {
        int e = tid + i * 128;
        int rc = e >> 3, cg = e & 7;
        int r = rc / 18, col = rc - r * 18;
        int gy = y - 1 + r, gx = xb - 1 + col;
        jst[i] = (e < 432);
        jok[i] = jst[i] && ((unsigned)gy < 96u) && ((unsigned)gx < 96u);
        joff[i] = (gy * 96 + gx) * 64 + cg * 8;
        jbase[i] = rc * 72 + cg * 8;
    }

    f32x4 acc0, acc1;
#pragma unroll
    for (int r = 0; r < 4; ++r) { acc0[r] = 0.f; acc1[r] = 0.f; }

    for (int j = 0; j < nsrc; ++j) {
        const int base = j * 2;
        __syncthreads();
        if (j == dslot) {
            // stage D = bf16(sum of npacc partials + dbias), interleaved f32
#pragma unroll
            for (int i = 0; i < 4; ++i) {
                if (jst[i]) {
                    u16x8 a;
                    if (jok[i]) {
                        const int cg8 = ((tid + i * 128) & 7) << 3;
                        f32x4 v0 = *(const f32x4*)(ddbias + cg8);
                        f32x4 v1 = *(const f32x4*)(ddbias + cg8 + 4);
                        for (int q2 = 0; q2 < npacc; ++q2) {
                            const float* pq = dpacc + (size_t)q2 * FRAME;
                            v0 += *(const f32x4*)(pq + joff[i]);
                            v1 += *(const f32x4*)(pq + joff[i] + 4);
                        }
#pragma unroll
                        for (int q = 0; q < 4; ++q) {
                            a[q] = bf16rnd(v0[q]);
                            a[4 + q] = bf16rnd(v1[q]);
                        }
                    } else {
#pragma unroll
                        for (int q = 0; q < 8; ++q) a[q] = 0;
                    }
                    *(u16x8*)(ldsH + jbase[i]) = a;
                }
            }
        } else {
            const ushort_t* sv = (j == 0) ? s0 : s1;
#pragma unroll
            for (int i = 0; i < 4; ++i) {
                if (jst[i]) {
                    u16x8 a;
                    if (jok[i]) {
                        a = *(const u16x8*)(sv + joff[i]);
                    } else {
#pragma unroll
                        for (int q = 0; q < 8; ++q) a[q] = 0;
                    }
                    *(u16x8*)(ldsH + jbase[i]) = a;
                }
            }
        }
        __syncthreads();
        bf16x8 pAh[5], pBh[5];
#pragma unroll
        for (int s = 0; s < 23; ++s) {
            if (s >= 5) {  // consume BEFORE refilling the slot
                const int u = s - 5;
                const bf16x8 Ah = pAh[u % 5];
                const bf16x8 Bh = pBh[u % 5];
                if (u & 1)
                    acc1 = __builtin_amdgcn_mfma_f32_16x16x32_bf16(Ah, Bh, acc1, 0, 0, 0);
                else
                    acc0 = __builtin_amdgcn_mfma_f32_16x16x32_bf16(Ah, Bh, acc0, 0, 0, 0);
            }
            if (s < 18) {
                const int t = s >> 1, cc2 = s & 1;
                const int ky = t / 3, kx = t % 3;
                const int cco = base + cc2;
                const ushort_t* ab =
                    wfrag + (((size_t)(t * KCfull + cco) * 4 + ot) * 64 + lane) * 8;
                pAh[s % 5] = *(const bf16x8*)ab;
                const int lb = (ky * 18 + n + kx) * 72 + cc2 * 32 + quad * 8;
                pBh[s % 5] = *(const bf16x8*)(ldsH + lb);
            }
        }
    }

    const int px = y * 96 + xb + n;
    f32x4 pa;
#pragma unroll
    for (int r = 0; r < 4; ++r) pa[r] = 0.f;
    if (addn) {
        const size_t eo = (size_t)px * 64 + ot * 16 + quad * 4;
        for (int q2 = 0; q2 < addn; ++q2)
            pa += *(const f32x4*)(dpacc + (size_t)q2 * FRAME + eo);
    }
    u16x4 hi4;
#pragma unroll
    for (int r = 0; r < 4; ++r) {
        int cout = ot * 16 + quad * 4 + r;
        float v = acc0[r] + acc1[r] + bias[cout];
        if (act) v = (v >= 0.f) ? v : 0.1f * v;
        if (addn) v += pa[r] + abias[cout];
        hi4[r] = bf16rnd(v);
    }
    *(u16x4*)(outhi + (size_t)px * 64 + ot * 16 + quad * 4) = hi4;
}

// ---------------------------------------------------------------------------
// Fused ow4 + modulated deformable conv, QUARTER-SPLIT: grid 576 x ngr4.
// Each block owns exactly ONE gather round gc (4 groups): computes the ~8
// ow4 out-tiles covering that round's offset/mask rows (ranges derived from
// g0 = gc*4), gathers once, writes pacc[gc] (interleaved f32). Per-block
// phase-2 chain ~halves vs half-split; block count doubles at ngr4=4.
// LDS 18.2 KB. hA/gather sources bf16-hi; cols bf16; 1-term MFMA.
// ---------------------------------------------------------------------------
__global__ __launch_bounds__(256) void dconv_fused_k(
    const ushort_t* __restrict__ sAh, const ushort_t* __restrict__ sBh,
    const ushort_t* __restrict__ hAh, const ushort_t* __restrict__ w4,
    const float* __restrict__ ob4, const ushort_t* __restrict__ dwf,
    int ngr4, float* __restrict__ pacc) {
    const int tid = threadIdx.x;
    const int lane = tid & 63;
    const int w = tid >> 6;
    const int gc = blockIdx.x % ngr4;
    const int seg = blockIdx.x / ngr4;
    const int xb = (seg % 6) * 16;
    const int y = seg / 6;
    const int n = lane & 15;
    const int quad = lane >> 4;

    __shared__ __align__(16) char smem[8704 + 9472];
    float* rawS = (float*)smem;               // up to [128][17] fp32
    ushort_t* ldsAH = (ushort_t*)(smem + 8704);   // 3888 ushorts (H-only)
    ushort_t* colsH = (ushort_t*)(smem + 8704);   // union with ldsA (4736 us)

    // ---- out-tile ranges for this gather round (4 groups) ----
    const int g0 = gc * 4;
    const int otO_s = (g0 * 18) >> 4;
    const int otO_e = (g0 * 18 + 71) >> 4;
    const int nO = otO_e - otO_s + 1;          // 5
    const int otM_s = (288 + g0 * 9) >> 4;
    const int otM_e = (288 + g0 * 9 + 35) >> 4;
    const int nM = otM_e - otM_s + 1;          // 3
    const int nt = nO + nM;                    // 8
    const int rowOffO = otO_s * 16;
    const int rowOffM = otM_s * 16 - nO * 16;

    // ---- phase 1: stage hA window (bf16-hi source, 1 load/job) ----
#pragma unroll
    for (int i = 0; i < 2; ++i) {
        int e = tid + i * 256;
        if (e < 432) {
            int rc = e >> 3, cg = e & 7;
            int r = rc / 18, col = rc - r * 18;
            int gy = y - 1 + r, gx = xb - 1 + col;
            bool ok = ((unsigned)gy < 96u) && ((unsigned)gx < 96u);
            u16x8 a;
            if (ok) {
                a = *(const u16x8*)(hAh + (gy * 96 + gx) * 64 + cg * 8);
            } else {
#pragma unroll
                for (int q = 0; q < 8; ++q) a[q] = 0;
            }
            *(u16x8*)(ldsAH + rc * 72 + cg * 8) = a;
        }
    }
    __syncthreads();

    // ---- phase 2: needed ow4 out-tiles (2/wave), 1 MFMA/step, depth-5 ----
#pragma unroll 1
    for (int j = 0; j < 2; ++j) {
        const int idx = j * 4 + w;
        if (idx >= nt) break;
        const int ot = (idx < nO) ? (otO_s + idx) : (otM_s + (idx - nO));
        f32x4 a0, a1;
#pragma unroll
        for (int r = 0; r < 4; ++r) { a0[r] = 0.f; a1[r] = 0.f; }
        bf16x8 pAh[5], pBh[5];
#pragma unroll
        for (int s = 0; s < 23; ++s) {
            if (s >= 5) {  // consume BEFORE refilling the slot
                const int u = s - 5;
                const bf16x8 Ah = pAh[u % 5];
                const bf16x8 Bh = pBh[u % 5];
                if (u & 1)
                    a1 = __builtin_amdgcn_mfma_f32_16x16x32_bf16(Ah, Bh, a1, 0, 0, 0);
                else
                    a0 = __builtin_amdgcn_mfma_f32_16x16x32_bf16(Ah, Bh, a0, 0, 0, 0);
            }
            if (s < 18) {
                const int t = s >> 1, cc2 = s & 1;
                const int ky = t / 3, kx = t % 3;
                const ushort_t* ab =
                    w4 + (((size_t)s * 28 + ot) * 64 + lane) * 8;
                pAh[s % 5] = *(const bf16x8*)ab;
                const int lb = (ky * 18 + n + kx) * 72 + cc2 * 32 + quad * 8;
                pBh[s % 5] = *(const bf16x8*)(ldsAH + lb);
            }
        }
#pragma unroll
        for (int r = 0; r < 4; ++r) {
            int cout = ot * 16 + quad * 4 + r;
            float v = a0[r] + a1[r] + (cout < 432 ? ob4[cout] : 0.f);
            rawS[(idx * 16 + quad * 4 + r) * 17 + n] = v;
        }
    }

    // ---- phase 3: single gather round -> bf16 cols -> 1-term MFMA ----
    f32x4 acc0, acc1;
#pragma unroll
    for (int r = 0; r < 4; ++r) { acc0[r] = 0.f; acc1[r] = 0.f; }

    __syncthreads();  // rawS ready / cols (ldsA) reuse safe
#pragma unroll
    for (int i = 0; i < 3; ++i) {
        int e = tid + i * 256;
        if (e < 576) {
            int p = e & 15;
            int r = e >> 4;  // 0..35
            int gl = r / 9, k = r - gl * 9;
            int g = gc * 4 + gl;
            float ry = rawS[(g * 18 + k * 2 + 0 - rowOffO) * 17 + p];
            float rx = rawS[(g * 18 + k * 2 + 1 - rowOffO) * 17 + p];
            float rm = rawS[(288 + g * 9 + k - rowOffM) * 17 + p];
            float oy = 5.f * (1.f - 2.f / (1.f + __expf(2.f * ry)));
            float ox = 5.f * (1.f - 2.f / (1.f + __expf(2.f * rx)));
            float m = 1.f / (1.f + __expf(-rm));
            float sy = oy + (float)(y - 1 + k / 3);
            float sx = ox + (float)(xb + p - 1 + k % 3);
            float fy0 = floorf(sy), fx0 = floorf(sx);
            float fy = sy - fy0, fx = sx - fx0;
            int y0 = (int)fy0, x0 = (int)fx0;
            int y1 = y0 + 1, x1 = x0 + 1;
            bool vy0 = (unsigned)y0 < 96u, vy1 = (unsigned)y1 < 96u;
            bool vx0 = (unsigned)x0 < 96u, vx1 = (unsigned)x1 < 96u;
            int cy0 = min(max(y0, 0), 95), cy1 = min(max(y1, 0), 95);
            int cx0 = min(max(x0, 0), 95), cx1 = min(max(x1, 0), 95);
            float w00 = (1.f - fy) * (1.f - fx) * ((vy0 && vx0) ? 1.f : 0.f);
            float w01 = (1.f - fy) * fx * ((vy0 && vx1) ? 1.f : 0.f);
            float w10 = fy * (1.f - fx) * ((vy1 && vx0) ? 1.f : 0.f);
            float w11 = fy * fx * ((vy1 && vx1) ? 1.f : 0.f);
            const ushort_t* src = (g < 8) ? sAh : sBh;
            int cb = (g & 7) * 8;
            int kbase = p * 296 + gl * 72 + k * 8;
            ushort_t hh[8];
            if (src) {
                u16x8 c00 = *(const u16x8*)(src + (cy0 * 96 + cx0) * 64 + cb);
                u16x8 c01 = *(const u16x8*)(src + (cy0 * 96 + cx1) * 64 + cb);
                u16x8 c10 = *(const u16x8*)(src + (cy1 * 96 + cx0) * 64 + cb);
                u16x8 c11 = *(const u16x8*)(src + (cy1 * 96 + cx1) * 64 + cb);
#pragma unroll
                for (int c = 0; c < 8; ++c) {
                    float v = w00 * bfh(c00[c]) + w01 * bfh(c01[c]) +
                              w10 * bfh(c10[c]) + w11 * bfh(c11[c]);
                    hh[c] = bf16rnd(v * m);
                }
            } else {
#pragma unroll
                for (int c = 0; c < 8; ++c) hh[c] = 0;
            }
            u32x4 H;
#pragma unroll
            for (int q = 0; q < 4; ++q)
                H[q] = (unsigned)hh[2 * q] | ((unsigned)hh[2 * q + 1] << 16);
            *(u32x4*)(colsH + kbase) = H;
        }
    }
    __syncthreads();
    bf16x8 qAh[4], qBh[4];
#pragma unroll
    for (int s = 0; s < 13; ++s) {
        if (s >= 4) {  // consume BEFORE refilling the slot
            const int u = s - 4;
            const bf16x8 Ah = qAh[u % 4];
            const bf16x8 Bh = qBh[u % 4];
            if (u & 1)
                acc1 = __builtin_amdgcn_mfma_f32_16x16x32_bf16(Ah, Bh, acc1, 0, 0, 0);
            else
                acc0 = __builtin_amdgcn_mfma_f32_16x16x32_bf16(Ah, Bh, acc0, 0, 0, 0);
        }
        if (s < 9) {
            const int cc = gc * 9 + s;
            const ushort_t* ab = dwf + (((size_t)cc * 4 + w) * 64 + lane) * 8;
            qAh[s % 4] = *(const bf16x8*)ab;
            const int lb = n * 296 + s * 32 + quad * 8;
            qBh[s % 4] = *(const bf16x8*)(colsH + lb);
        }
    }

    const int pidx = y * 96 + xb + n;
    f32x4 sv;
#pragma unroll
    for (int r = 0; r < 4; ++r) sv[r] = acc0[r] + acc1[r];
    *(f32x4*)(pacc + (size_t)gc * FRAME + (size_t)pidx * 64 + w * 16 +
              quad * 4) = sv;
}

// ---------------------------------------------------------------------------
// MFMA fusion: 1x1 conv over bf16-hi [featBh[t], featFh[t]] (K=128) + bias
// + x. Weight hi/lo kept (AhBh + AlBh): final-output precision.
// ---------------------------------------------------------------------------
__global__ __launch_bounds__(128) void fusem_k(
    const ushort_t* __restrict__ featBh, const ushort_t* __restrict__ featFh,
    const float* __restrict__ x, const ushort_t* __restrict__ wfrag,
    const float* __restrict__ bias, float* __restrict__ out) {
    const int tid = threadIdx.x;
    const int lane = tid & 63;
    const int w = tid >> 6;
    const int h = blockIdx.x & 1;
    const int bseg = blockIdx.x >> 1;
    const int t = blockIdx.y;
    const int ot = h * 2 + w;
    const int xb = (bseg % 6) * 16;
    const int y = bseg / 6;
    const int n = lane & 15;
    const int quad = lane >> 4;

    __shared__ __align__(16) ushort_t ldsH[16 * 144];

    const int p = tid >> 3, cg = tid & 7;
    const int off = ((y * 96 + xb + p) * 64 + cg * 8);
#pragma unroll
    for (int i = 0; i < 2; ++i) {  // i=0: featB (ch 0-63), i=1: featF (64-127)
        const ushort_t* sv =
            (i == 0 ? featBh : featFh) + (size_t)t * FRAME;
        u16x8 a = *(const u16x8*)(sv + off);
        *(u16x8*)(ldsH + p * 144 + i * 64 + cg * 8) = a;
    }
    __syncthreads();

    f32x4 acc0, acc1;
#pragma unroll
    for (int r = 0; r < 4; ++r) { acc0[r] = 0.f; acc1[r] = 0.f; }
    const size_t hlOff = (size_t)4 * 4 * 512;
#pragma unroll
    for (int cc = 0; cc < 4; ++cc) {
        const ushort_t* ab = wfrag + (((size_t)cc * 4 + ot) * 64 + lane) * 8;
        bf16x8 Ah = *(const bf16x8*)ab;
        bf16x8 Al = *(const bf16x8*)(ab + hlOff);
        int lb = n * 144 + cc * 32 + quad * 8;
        bf16x8 Bh = *(const bf16x8*)(ldsH + lb);
        if (cc & 1) {
            acc1 = __builtin_amdgcn_mfma_f32_16x16x32_bf16(Ah, Bh, acc1, 0, 0, 0);
            acc1 = __builtin_amdgcn_mfma_f32_16x16x32_bf16(Al, Bh, acc1, 0, 0, 0);
        } else {
            acc0 = __builtin_amdgcn_mfma_f32_16x16x32_bf16(Ah, Bh, acc0, 0, 0, 0);
            acc0 = __builtin_amdgcn_mfma_f32_16x16x32_bf16(Al, Bh, acc0, 0, 0, 0);
        }
    }

    const int pidx = y * 96 + xb + n;
    const float* xt = x + (size_t)t * FRAME;
    float* od = out + (size_t)t * FRAME;
#pragma unroll
    for (int r = 0; r < 4; ++r) {
        int cout = ot * 16 + quad * 4 + r;
        size_t o2 = (size_t)cout * HW96 + pidx;
        od[o2] = acc0[r] + acc1[r] + bias[cout] + xt[o2];
    }
}

// ---------------------------------------------------------------------------
extern "C" void kernel_launch(void* const* d_in, const int* in_sizes, int n_in,
                              void* d_out, int out_size, void* d_ws,
                              size_t ws_size, hipStream_t stream) {
    const float* x = (const float*)d_in[0];
    auto gp = [&](int i) { return (const float*)d_in[i]; };

    struct DirP {
        const float *dw, *db, *ow1, *ob1, *ow2, *ob2, *ow3, *ob3, *ow4, *ob4,
            *bw1, *bb1, *bw2, *bb2;
    };
    DirP Pb{gp(1), gp(2), gp(3), gp(4), gp(5), gp(6), gp(7),
            gp(8), gp(9), gp(10), gp(11), gp(12), gp(13), gp(14)};
    DirP Pf{gp(15), gp(16), gp(17), gp(18), gp(19), gp(20), gp(21),
            gp(22), gp(23), gp(24), gp(25), gp(26), gp(27), gp(28)};
    const float* fus_w = gp(29);
    const float* fus_b = gp(30);

    // ---- workspace carve-up: all feature/intermediate bufs bf16-hi ushort --
    ushort_t* xh = (ushort_t*)d_ws;                       // 8 frames
    ushort_t* featBh = xh + (size_t)8 * FRAME;            // 8 frames
    ushort_t* featFh = featBh + (size_t)8 * FRAME;        // 8 frames
    ushort_t* hAh = featFh + (size_t)8 * FRAME;           // 1 frame
    ushort_t* hBh = hAh + FRAME;                          // 1 frame
    float* pacc = (float*)((((uintptr_t)(hBh + FRAME)) + 15) & ~(uintptr_t)15);
    ushort_t* fragp = (ushort_t*)(pacc + (size_t)4 * FRAME);

    auto falloc = [&](size_t nelem) {
        ushort_t* p = fragp;
        fragp += nelem;
        return p;
    };

    struct DirW { ushort_t *ow1, *ow2, *ow3, *ow4, *bw1, *bw2, *dw; int bw1KC; };
    FragJobs fj;
    int nf = 0;
    auto fjob = [&](const float* src, int O, int I, int OT, int KC) {
        ushort_t* dst = falloc((size_t)2 * 9 * KC * OT * 512);
        fj.j[nf++] = FragJob{src, dst, O, I, OT, KC, 0};
        return dst;
    };
    auto fjobd = [&](const float* src) {
        ushort_t* dst = falloc((size_t)2 * 36 * 4 * 512);
        fj.j[nf++] = FragJob{src, dst, 64, 128, 4, 36, 1};
        return dst;
    };
    DirW Wb, Wf;
    Wb.ow1 = fjob(Pb.ow1, 64, 192, 4, 6);
    Wb.ow2 = fjob(Pb.ow2, 64, 64, 4, 2);
    Wb.ow3 = fjob(Pb.ow3, 64, 64, 4, 2);
    Wb.ow4 = fjob(Pb.ow4, 432, 64, 28, 2);
    Wb.bw1 = fjob(Pb.bw1, 64, 128, 4, 4);
    Wb.bw1KC = 4;
    Wb.bw2 = fjob(Pb.bw2, 64, 64, 4, 2);
    Wb.dw = fjobd(Pb.dw);
    Wf.ow1 = fjob(Pf.ow1, 64, 192, 4, 6);
    Wf.ow2 = fjob(Pf.ow2, 64, 64, 4, 2);
    Wf.ow3 = fjob(Pf.ow3, 64, 64, 4, 2);
    Wf.ow4 = fjob(Pf.ow4, 432, 64, 28, 2);
    Wf.bw1 = fjob(Pf.bw1, 64, 192, 4, 6);
    Wf.bw1KC = 6;
    Wf.bw2 = fjob(Pf.bw2, 64, 64, 4, 2);
    Wf.dw = fjobd(Pf.dw);
    // fusion 1x1 weights (mode 2): O=64, I=128, OT=4, KC=4
    ushort_t* Wfus = falloc((size_t)2 * 4 * 4 * 512);
    fj.j[nf++] = FragJob{fus_w, Wfus, 64, 128, 4, 4, 2};
    frag_all_k<<<dim3(1008, 15), 256, 0, stream>>>(fj);

    pack_tr_k<<<dim3(144, 8), 256, 0, stream>>>(x, xh);

    auto convh = [&](const ushort_t* a, const ushort_t* b, const ushort_t* c2,
                     const ushort_t* frag, int KCfull, const float* bias,
                     ushort_t* out, int act) {
        const ushort_t* srcs[3] = {a, b, c2};
        const ushort_t* S[3] = {nullptr, nullptr, nullptr};
        int B[3] = {0, 0, 0};
        int ns = 0;
        for (int j = 0; j < 3; ++j)
            if (srcs[j]) {
                S[ns] = srcs[j];
                B[ns] = j * 2;
                ++ns;
            }
        convh_k<<<1152, 128, 0, stream>>>(S[0], S[1], S[2], B[0], B[1], B[2],
                                          ns, frag, KCfull, bias, out, act);
    };

    auto convb = [&](const ushort_t* a, const ushort_t* b, int withD,
                     int npacc, const float* ddbias, const ushort_t* frag,
                     int KCfull, const float* bias, int addn,
                     const float* abias, ushort_t* out, int act) {
        const ushort_t* S[2] = {nullptr, nullptr};
        int ns = 0;
        if (a) S[ns++] = a;
        if (b) S[ns++] = b;
        int dslot = -1;
        if (withD) { dslot = ns; ++ns; }
        convb_k<<<1152, 128, 0, stream>>>(S[0], S[1], ns, dslot, pacc, npacc,
                                          ddbias, frag, KCfull, bias, addn,
                                          abias, out, act);
    };

    for (int dir = 0; dir < 2; ++dir) {  // 0 = backward, 1 = forward
        const DirP& P = dir ? Pf : Pb;
        const DirW& W = dir ? Wf : Wb;
        ushort_t* feath = dir ? featFh : featBh;
        const ushort_t* prev1h = nullptr;
        const ushort_t* prev2h = nullptr;
        for (int i = 0; i < 8; ++i) {
            int idx = dir ? i : 7 - i;
            const ushort_t* curh = xh + (size_t)idx * FRAME;
            int ngr4 = 0;
            if (i > 0) {
                // offset/mask path: pure bf16-hi (convh)
                convh(prev1h, curh, prev2h, W.ow1, 6, P.ob1, hAh, 1);
                convh(hAh, nullptr, nullptr, W.ow2, 2, P.ob2, hBh, 1);
                convh(hBh, nullptr, nullptr, W.ow3, 2, P.ob3, hAh, 1);
                ngr4 = (prev2h != nullptr) ? 4 : 2;
                dconv_fused_k<<<576 * ngr4, 256, 0, stream>>>(
                    prev1h, prev2h, hAh, W.ow4, P.ob4, W.dw, ngr4, pacc);
            }
            ushort_t* dsth = feath + (size_t)idx * FRAME;
            // bw1: hi-only, D staged as sum of ngr4 pacc partials
            if (dir == 0) {
                convb(curh, nullptr, ngr4 ? 1 : 0, ngr4, P.db, W.bw1,
                      W.bw1KC, P.bb1, 0, nullptr, hBh, 1);
            } else {
                convb(curh, featBh + (size_t)idx * FRAME, ngr4 ? 1 : 0, ngr4,
                      P.db, W.bw1, W.bw1KC, P.bb1, 0, nullptr, hBh, 1);
            }
            // bw2: hi-only + sum of ngr4 pacc partials + dbias in epilogue
            convb(hBh, nullptr, 0, 0, nullptr, W.bw2, 2, P.bb2, ngr4, P.db,
                  dsth, 0);
            prev2h = prev1h;
            prev1h = dsth;
        }
    }

    fusem_k<<<dim3(1152, 8), 128, 0, stream>>>(featBh, featFh, x, Wfus,
                                               fus_b, (float*)d_out);
}

// Round 17
// 1063.649 us; speedup vs baseline: 1.0864x; 1.0864x over previous
//
#include <hip/hip_runtime.h>
#include <cstddef>
#include <cstdint>

#define HW96 9216
#define FRAME (64 * 9216)

typedef unsigned short ushort_t;
typedef __attribute__((ext_vector_type(8))) short bf16x8;
typedef __attribute__((ext_vector_type(4))) float f32x4;
typedef __attribute__((ext_vector_type(4))) unsigned u32x4;
typedef __attribute__((ext_vector_type(8))) ushort_t u16x8;
typedef __attribute__((ext_vector_type(4))) ushort_t u16x4;

__device__ __forceinline__ void split16(float v, ushort_t& h, ushort_t& l) {
    unsigned u = __float_as_uint(v);
    h = (ushort_t)(u >> 16);
    float rem = v - __uint_as_float(u & 0xFFFF0000u);
    unsigned r = __float_as_uint(rem);
    l = (ushort_t)((r + 0x7FFFu + ((r >> 16) & 1u)) >> 16);
}
__device__ __forceinline__ ushort_t bf16rnd(float v) {
    unsigned u = __float_as_uint(v);
    return (ushort_t)((u + 0x7FFFu + ((u >> 16) & 1u)) >> 16);
}
__device__ __forceinline__ float bfh(ushort_t h) {
    return __uint_as_float(((unsigned)h) << 16);
}

// ---------------------------------------------------------------------------
// MFMA A-fragment prepack (16x16x32) with bf16 hi/lo split.
// mode 0 (3x3 conv): layout [hl][t][cc][ot][lane][j]; K = cin chunks of 32.
// mode 1 (dconv):    layout [hl][cc][ot][lane][j]; K = g*72 + tap*8 + c.
// mode 2 (1x1 conv): layout [hl][cc][ot][lane][j]; K = cin chunks of 32.
// ---------------------------------------------------------------------------
struct FragJob { const float* src; ushort_t* dst; int O, I, OT, KC, mode; };
struct FragJobs { FragJob j[15]; };

__global__ __launch_bounds__(256) void frag_all_k(FragJobs jobs) {
    const FragJob& J = jobs.j[blockIdx.y];
    int idx = blockIdx.x * 256 + threadIdx.x;
    int total = ((J.mode == 0) ? 9 : 1) * J.KC * J.OT * 512;
    if (idx >= total) return;
    int jj = idx & 7;
    int lane = (idx >> 3) & 63;
    int rem = idx >> 9;
    int ot = rem % J.OT;
    rem /= J.OT;
    int cc = rem % J.KC;
    int t = rem / J.KC;
    int o = ot * 16 + (lane & 15);
    float wv = 0.f;
    if (J.mode == 0) {
        int ci = cc * 32 + (lane >> 4) * 8 + jj;
        if (o < J.O && ci < J.I) wv = J.src[(o * J.I + ci) * 9 + t];
    } else if (J.mode == 1) {
        int K = cc * 32 + (lane >> 4) * 8 + jj;
        int g = K / 72, r2 = K % 72;
        int tap = r2 >> 3, c = r2 & 7;
        int ci = g * 8 + c;
        if (o < J.O && ci < J.I) wv = J.src[(o * J.I + ci) * 9 + tap];
    } else {  // mode 2: 1x1
        int ci = cc * 32 + (lane >> 4) * 8 + jj;
        if (o < J.O && ci < J.I) wv = J.src[o * J.I + ci];
    }
    ushort_t h, l;
    split16(wv, h, l);
    J.dst[idx] = h;
    J.dst[total + idx] = l;
}

// ---------------------------------------------------------------------------
// Transposing pack: planar fp32 -> interleaved bf16-hi shadow only.
// ---------------------------------------------------------------------------
__global__ __launch_bounds__(256) void pack_tr_k(const float* __restrict__ src,
                                                 ushort_t* __restrict__ dsth) {
    const int t = blockIdx.y;
    const int px0 = blockIdx.x * 64;
    __shared__ ushort_t tile[64 * 65];
    const float* s = src + (size_t)t * FRAME;
    ushort_t* dh = dsth + (size_t)t * FRAME;
#pragma unroll
    for (int it = 0; it < 16; ++it) {
        int e = it * 256 + threadIdx.x;
        int p = e & 63, ch = e >> 6;
        tile[ch * 65 + p] = bf16rnd(s[(size_t)ch * HW96 + px0 + p]);
    }
    __syncthreads();
#pragma unroll
    for (int it = 0; it < 16; ++it) {
        int e = it * 256 + threadIdx.x;
        int ch = e & 63, p = e >> 6;
        dh[(size_t)(px0 + p) * 64 + ch] = tile[ch * 65 + p];
    }
}

// ---------------------------------------------------------------------------
// Hi-only bf16 MFMA 3x3 conv (offset/mask path: ow1/ow2/ow3).
// Sources bf16-hi interleaved; 1 u16x8/job staging; H-only LDS; 1 MFMA/step.
// ---------------------------------------------------------------------------
__global__ __launch_bounds__(128, 3) void convh_k(
    const ushort_t* __restrict__ s0, const ushort_t* __restrict__ s1,
    const ushort_t* __restrict__ s2, int b0, int b1, int b2, int nsrc,
    const ushort_t* __restrict__ wfrag, int KCfull,
    const float* __restrict__ bias, ushort_t* __restrict__ outhi, int act) {
    const int tid = threadIdx.x;
    const int lane = tid & 63;
    const int w = tid >> 6;
    const int h = blockIdx.x & 1;
    const int bseg = blockIdx.x >> 1;
    const int ot = h * 2 + w;
    const int xb = (bseg % 6) * 16;
    const int y = bseg / 6;
    const int n = lane & 15;
    const int quad = lane >> 4;

    __shared__ __align__(16) ushort_t ldsH[3 * 18 * 72];

    int jst[4], jok[4], joff[4], jbase[4];
#pragma unroll
    for (int i = 0; i < 4; ++i) {
        int e = tid + i * 128;
        int rc = e >> 3, cg = e & 7;
        int r = rc / 18, col = rc - r * 18;
        int gy = y - 1 + r, gx = xb - 1 + col;
        jst[i] = (e < 432);
        jok[i] = jst[i] && ((unsigned)gy < 96u) && ((unsigned)gx < 96u);
        joff[i] = (gy * 96 + gx) * 64 + cg * 8;
        jbase[i] = rc * 72 + cg * 8;
    }

    f32x4 acc0, acc1;
#pragma unroll
    for (int r = 0; r < 4; ++r) { acc0[r] = 0.f; acc1[r] = 0.f; }

    for (int j = 0; j < nsrc; ++j) {
        const ushort_t* sv = (j == 0) ? s0 : (j == 1 ? s1 : s2);
        const int base = (j == 0) ? b0 : (j == 1 ? b1 : b2);
        __syncthreads();
#pragma unroll
        for (int i = 0; i < 4; ++i) {
            if (jst[i]) {
                u16x8 a;
                if (jok[i]) {
                    a = *(const u16x8*)(sv + joff[i]);
                } else {
#pragma unroll
                    for (int q = 0; q < 8; ++q) a[q] = 0;
                }
                *(u16x8*)(ldsH + jbase[i]) = a;
            }
        }
        __syncthreads();
        bf16x8 pAh[5], pBh[5];
#pragma unroll
        for (int s = 0; s < 23; ++s) {
            if (s >= 5) {  // consume BEFORE refilling the slot
                const int u = s - 5;
                const bf16x8 Ah = pAh[u % 5];
                const bf16x8 Bh = pBh[u % 5];
                if (u & 1)
                    acc1 = __builtin_amdgcn_mfma_f32_16x16x32_bf16(Ah, Bh, acc1, 0, 0, 0);
                else
                    acc0 = __builtin_amdgcn_mfma_f32_16x16x32_bf16(Ah, Bh, acc0, 0, 0, 0);
            }
            if (s < 18) {
                const int t = s >> 1, cc2 = s & 1;
                const int ky = t / 3, kx = t % 3;
                const int ccor = base + cc2;
                const ushort_t* ab =
                    wfrag + (((size_t)(t * KCfull + ccor) * 4 + ot) * 64 + lane) * 8;
                pAh[s % 5] = *(const bf16x8*)ab;
                const int lb = (ky * 18 + n + kx) * 72 + cc2 * 32 + quad * 8;
                pBh[s % 5] = *(const bf16x8*)(ldsH + lb);
            }
        }
    }

    const int px = y * 96 + xb + n;
    u16x4 hi4;
#pragma unroll
    for (int r = 0; r < 4; ++r) {
        int cout = ot * 16 + quad * 4 + r;
        float v = acc0[r] + acc1[r] + bias[cout];
        if (act) v = (v >= 0.f) ? v : 0.1f * v;
        hi4[r] = bf16rnd(v);
    }
    *(u16x4*)(outhi + (size_t)px * 64 + ot * 16 + quad * 4) = hi4;
}

// ---------------------------------------------------------------------------
// Feature-path hi-only bf16 MFMA 3x3 conv (bw1/bw2).
// dslot stages D = bf16(pacc0+pacc1+dbias) from the interleaved pacc pair;
// bw2 epilogue adds pacc pair + abias (fp32 vector loads). 1 MFMA/K-step.
// ---------------------------------------------------------------------------
__global__ __launch_bounds__(128, 3) void convb_k(
    const ushort_t* __restrict__ s0, const ushort_t* __restrict__ s1,
    int nsrc, int dslot, const float* __restrict__ dpacc,
    const float* __restrict__ ddbias, const ushort_t* __restrict__ wfrag,
    int KCfull, const float* __restrict__ bias,
    const float* __restrict__ addsrc, const float* __restrict__ addsrc2,
    const float* __restrict__ abias, ushort_t* __restrict__ outhi, int act) {
    const int tid = threadIdx.x;
    const int lane = tid & 63;
    const int w = tid >> 6;
    const int h = blockIdx.x & 1;
    const int bseg = blockIdx.x >> 1;
    const int ot = h * 2 + w;
    const int xb = (bseg % 6) * 16;
    const int y = bseg / 6;
    const int n = lane & 15;
    const int quad = lane >> 4;

    __shared__ __align__(16) ushort_t ldsH[3 * 18 * 72];

    int jst[4], jok[4], joff[4], jbase[4];
#pragma unroll
    for (int i = 0; i < 4; ++i) {
        int e = tid + i * 128;
        int rc = e >> 3, cg = e & 7;
        int r = rc / 18, col = rc - r * 18;
        int gy = y - 1 + r, gx = xb - 1 + col;
        jst[i] = (e < 432);
        jok[i] = jst[i] && ((unsigned)gy < 96u) && ((unsigned)gx < 96u);
        joff[i] = (gy * 96 + gx) * 64 + cg * 8;
        jbase[i] = rc * 72 + cg * 8;
    }

    f32x4 acc0, acc1;
#pragma unroll
    for (int r = 0; r < 4; ++r) { acc0[r] = 0.f; acc1[r] = 0.f; }

    for (int j = 0; j < nsrc; ++j) {
        const int base = j * 2;
        __syncthreads();
        if (j == dslot) {
            // stage D = bf16(pacc0 + pacc1 + dbias) (interleaved f32 pair)
#pragma unroll
            for (int i = 0; i < 4; ++i) {
                if (jst[i]) {
                    u16x8 a;
                    if (jok[i]) {
                        const int cg8 = ((tid + i * 128) & 7) << 3;
                        f32x4 a0 = *(const f32x4*)(dpacc + joff[i]);
                        f32x4 a1 = *(const f32x4*)(dpacc + joff[i] + 4);
                        f32x4 b0 = *(const f32x4*)(dpacc + FRAME + joff[i]);
                        f32x4 b1 = *(const f32x4*)(dpacc + FRAME + joff[i] + 4);
                        f32x4 d0 = *(const f32x4*)(ddbias + cg8);
                        f32x4 d1 = *(const f32x4*)(ddbias + cg8 + 4);
#pragma unroll
                        for (int q = 0; q < 4; ++q) {
                            a[q] = bf16rnd(a0[q] + b0[q] + d0[q]);
                            a[4 + q] = bf16rnd(a1[q] + b1[q] + d1[q]);
                        }
                    } else {
#pragma unroll
                        for (int q = 0; q < 8; ++q) a[q] = 0;
                    }
                    *(u16x8*)(ldsH + jbase[i]) = a;
                }
            }
        } else {
            const ushort_t* sv = (j == 0) ? s0 : s1;
#pragma unroll
            for (int i = 0; i < 4; ++i) {
                if (jst[i]) {
                    u16x8 a;
                    if (jok[i]) {
                        a = *(const u16x8*)(sv + joff[i]);
                    } else {
#pragma unroll
                        for (int q = 0; q < 8; ++q) a[q] = 0;
                    }
                    *(u16x8*)(ldsH + jbase[i]) = a;
                }
            }
        }
        __syncthreads();
        bf16x8 pAh[5], pBh[5];
#pragma unroll
        for (int s = 0; s < 23; ++s) {
            if (s >= 5) {  // consume BEFORE refilling the slot
                const int u = s - 5;
                const bf16x8 Ah = pAh[u % 5];
                const bf16x8 Bh = pBh[u % 5];
                if (u & 1)
                    acc1 = __builtin_amdgcn_mfma_f32_16x16x32_bf16(Ah, Bh, acc1, 0, 0, 0);
                else
                    acc0 = __builtin_amdgcn_mfma_f32_16x16x32_bf16(Ah, Bh, acc0, 0, 0, 0);
            }
            if (s < 18) {
                const int t = s >> 1, cc2 = s & 1;
                const int ky = t / 3, kx = t % 3;
                const int cco = base + cc2;
                const ushort_t* ab =
                    wfrag + (((size_t)(t * KCfull + cco) * 4 + ot) * 64 + lane) * 8;
                pAh[s % 5] = *(const bf16x8*)ab;
                const int lb = (ky * 18 + n + kx) * 72 + cc2 * 32 + quad * 8;
                pBh[s % 5] = *(const bf16x8*)(ldsH + lb);
            }
        }
    }

    const int px = y * 96 + xb + n;
    f32x4 pa, pb;
#pragma unroll
    for (int r = 0; r < 4; ++r) { pa[r] = 0.f; pb[r] = 0.f; }
    if (addsrc) {
        pa = *(const f32x4*)(addsrc + (size_t)px * 64 + ot * 16 + quad * 4);
        pb = *(const f32x4*)(addsrc2 + (size_t)px * 64 + ot * 16 + quad * 4);
    }
    u16x4 hi4;
#pragma unroll
    for (int r = 0; r < 4; ++r) {
        int cout = ot * 16 + quad * 4 + r;
        float v = acc0[r] + acc1[r] + bias[cout];
        if (act) v = (v >= 0.f) ? v : 0.1f * v;
        if (addsrc) v += pa[r] + pb[r] + abias[cout];
        hi4[r] = bf16rnd(v);
    }
    *(u16x4*)(outhi + (size_t)px * 64 + ot * 16 + quad * 4) = hi4;
}

// ---------------------------------------------------------------------------
// Fused ow4 + modulated deformable conv, HALF-SPLIT: grid 1152 = 576 seg x 2.
// hA bf16-hi; gather reads bf16-hi shadows; cols single bf16; 1-term MFMA.
// pacc INTERLEAVED [h][px][64] f32.
// ---------------------------------------------------------------------------
__global__ __launch_bounds__(256) void dconv_fused_k(
    const ushort_t* __restrict__ sAh, const ushort_t* __restrict__ sBh,
    const ushort_t* __restrict__ hAh, const ushort_t* __restrict__ w4,
    const float* __restrict__ ob4, const ushort_t* __restrict__ dwf,
    int ngr4, float* __restrict__ pacc) {
    const int tid = threadIdx.x;
    const int lane = tid & 63;
    const int w = tid >> 6;
    const int h = blockIdx.x & 1;
    const int seg = blockIdx.x >> 1;
    const int xb = (seg % 6) * 16;
    const int y = seg / 6;
    const int n = lane & 15;
    const int quad = lane >> 4;

    __shared__ __align__(16) char smem[15232 + 9472];
    float* rawS = (float*)smem;               // up to [224][17] fp32
    ushort_t* ldsAH = (ushort_t*)(smem + 15232);  // 3888 ushorts (H-only)
    ushort_t* colsH = (ushort_t*)(smem + 15232);  // union with ldsA (4736 us)

    const int nrounds = ngr4 >> 1;   // 1 or 2
    const int ng = nrounds * 4;      // groups per half
    const int g0 = h * ng;
    const int otO_s = (g0 * 18) >> 4;
    const int otO_e = (g0 * 18 + ng * 18 - 1) >> 4;
    const int nO = otO_e - otO_s + 1;
    const int otM_s = (288 + g0 * 9) >> 4;
    const int otM_e = (288 + g0 * 9 + ng * 9 - 1) >> 4;
    const int nM = otM_e - otM_s + 1;
    const int nt = nO + nM;          // 14 (ngr4=4) or 8 (ngr4=2)
    const int rowOffO = otO_s * 16;
    const int rowOffM = otM_s * 16 - nO * 16;

    // ---- phase 1: stage hA window (bf16-hi source, 1 load/job) ----
#pragma unroll
    for (int i = 0; i < 2; ++i) {
        int e = tid + i * 256;
        if (e < 432) {
            int rc = e >> 3, cg = e & 7;
            int r = rc / 18, col = rc - r * 18;
            int gy = y - 1 + r, gx = xb - 1 + col;
            bool ok = ((unsigned)gy < 96u) && ((unsigned)gx < 96u);
            u16x8 a;
            if (ok) {
                a = *(const u16x8*)(hAh + (gy * 96 + gx) * 64 + cg * 8);
            } else {
#pragma unroll
                for (int q = 0; q < 8; ++q) a[q] = 0;
            }
            *(u16x8*)(ldsAH + rc * 72 + cg * 8) = a;
        }
    }
    __syncthreads();

    // ---- phase 2: needed ow4 out-tiles, 1 MFMA/step, depth-5 pipeline ----
#pragma unroll 1
    for (int j = 0; j < 4; ++j) {
        const int idx = j * 4 + w;
        if (idx >= nt) break;
        const int ot = (idx < nO) ? (otO_s + idx) : (otM_s + (idx - nO));
        f32x4 a0, a1;
#pragma unroll
        for (int r = 0; r < 4; ++r) { a0[r] = 0.f; a1[r] = 0.f; }
        bf16x8 pAh[5], pBh[5];
#pragma unroll
        for (int s = 0; s < 23; ++s) {
            if (s >= 5) {  // consume BEFORE refilling the slot
                const int u = s - 5;
                const bf16x8 Ah = pAh[u % 5];
                const bf16x8 Bh = pBh[u % 5];
                if (u & 1)
                    a1 = __builtin_amdgcn_mfma_f32_16x16x32_bf16(Ah, Bh, a1, 0, 0, 0);
                else
                    a0 = __builtin_amdgcn_mfma_f32_16x16x32_bf16(Ah, Bh, a0, 0, 0, 0);
            }
            if (s < 18) {
                const int t = s >> 1, cc2 = s & 1;
                const int ky = t / 3, kx = t % 3;
                const ushort_t* ab =
                    w4 + (((size_t)s * 28 + ot) * 64 + lane) * 8;
                pAh[s % 5] = *(const bf16x8*)ab;
                const int lb = (ky * 18 + n + kx) * 72 + cc2 * 32 + quad * 8;
                pBh[s % 5] = *(const bf16x8*)(ldsAH + lb);
            }
        }
#pragma unroll
        for (int r = 0; r < 4; ++r) {
            int cout = ot * 16 + quad * 4 + r;
            float v = a0[r] + a1[r] + (cout < 432 ? ob4[cout] : 0.f);
            rawS[(idx * 16 + quad * 4 + r) * 17 + n] = v;
        }
    }

    // ---- phase 3: gather (bf16-hi) -> bf16 cols -> dconv MFMA (1-term) ----
    f32x4 acc0, acc1;
#pragma unroll
    for (int r = 0; r < 4; ++r) { acc0[r] = 0.f; acc1[r] = 0.f; }

    for (int gci = 0; gci < nrounds; ++gci) {
        const int gc = h * nrounds + gci;
        __syncthreads();  // rawS ready / cols (ldsA) reuse safe
#pragma unroll
        for (int i = 0; i < 3; ++i) {
            int e = tid + i * 256;
            if (e < 576) {
                int p = e & 15;
                int r = e >> 4;  // 0..35
                int gl = r / 9, k = r - gl * 9;
                int g = gc * 4 + gl;
                float ry = rawS[(g * 18 + k * 2 + 0 - rowOffO) * 17 + p];
                float rx = rawS[(g * 18 + k * 2 + 1 - rowOffO) * 17 + p];
                float rm = rawS[(288 + g * 9 + k - rowOffM) * 17 + p];
                float oy = 5.f * (1.f - 2.f / (1.f + __expf(2.f * ry)));
                float ox = 5.f * (1.f - 2.f / (1.f + __expf(2.f * rx)));
                float m = 1.f / (1.f + __expf(-rm));
                float sy = oy + (float)(y - 1 + k / 3);
                float sx = ox + (float)(xb + p - 1 + k % 3);
                float fy0 = floorf(sy), fx0 = floorf(sx);
                float fy = sy - fy0, fx = sx - fx0;
                int y0 = (int)fy0, x0 = (int)fx0;
                int y1 = y0 + 1, x1 = x0 + 1;
                bool vy0 = (unsigned)y0 < 96u, vy1 = (unsigned)y1 < 96u;
                bool vx0 = (unsigned)x0 < 96u, vx1 = (unsigned)x1 < 96u;
                int cy0 = min(max(y0, 0), 95), cy1 = min(max(y1, 0), 95);
                int cx0 = min(max(x0, 0), 95), cx1 = min(max(x1, 0), 95);
                float w00 = (1.f - fy) * (1.f - fx) * ((vy0 && vx0) ? 1.f : 0.f);
                float w01 = (1.f - fy) * fx * ((vy0 && vx1) ? 1.f : 0.f);
                float w10 = fy * (1.f - fx) * ((vy1 && vx0) ? 1.f : 0.f);
                float w11 = fy * fx * ((vy1 && vx1) ? 1.f : 0.f);
                const ushort_t* src = (g < 8) ? sAh : sBh;
                int cb = (g & 7) * 8;
                int kbase = p * 296 + gl * 72 + k * 8;
                ushort_t hh[8];
                if (src) {
                    u16x8 c00 = *(const u16x8*)(src + (cy0 * 96 + cx0) * 64 + cb);
                    u16x8 c01 = *(const u16x8*)(src + (cy0 * 96 + cx1) * 64 + cb);
                    u16x8 c10 = *(const u16x8*)(src + (cy1 * 96 + cx0) * 64 + cb);
                    u16x8 c11 = *(const u16x8*)(src + (cy1 * 96 + cx1) * 64 + cb);
#pragma unroll
                    for (int c = 0; c < 8; ++c) {
                        float v = w00 * bfh(c00[c]) + w01 * bfh(c01[c]) +
                                  w10 * bfh(c10[c]) + w11 * bfh(c11[c]);
                        hh[c] = bf16rnd(v * m);
                    }
                } else {
#pragma unroll
                    for (int c = 0; c < 8; ++c) hh[c] = 0;
                }
                u32x4 H;
#pragma unroll
                for (int q = 0; q < 4; ++q)
                    H[q] = (unsigned)hh[2 * q] | ((unsigned)hh[2 * q + 1] << 16);
                *(u32x4*)(colsH + kbase) = H;
            }
        }
        __syncthreads();
        bf16x8 qAh[4], qBh[4];
#pragma unroll
        for (int s = 0; s < 13; ++s) {
            if (s >= 4) {  // consume BEFORE refilling the slot
                const int u = s - 4;
                const bf16x8 Ah = qAh[u % 4];
                const bf16x8 Bh = qBh[u % 4];
                if (u & 1)
                    acc1 = __builtin_amdgcn_mfma_f32_16x16x32_bf16(Ah, Bh, acc1, 0, 0, 0);
                else
                    acc0 = __builtin_amdgcn_mfma_f32_16x16x32_bf16(Ah, Bh, acc0, 0, 0, 0);
            }
            if (s < 9) {
                const int cc = gc * 9 + s;
                const ushort_t* ab = dwf + (((size_t)cc * 4 + w) * 64 + lane) * 8;
                qAh[s % 4] = *(const bf16x8*)ab;
                const int lb = n * 296 + s * 32 + quad * 8;
                qBh[s % 4] = *(const bf16x8*)(colsH + lb);
            }
        }
    }

    const int pidx = y * 96 + xb + n;
    f32x4 sv;
#pragma unroll
    for (int r = 0; r < 4; ++r) sv[r] = acc0[r] + acc1[r];
    *(f32x4*)(pacc + (size_t)h * FRAME + (size_t)pidx * 64 + w * 16 +
              quad * 4) = sv;
}

// ---------------------------------------------------------------------------
// MFMA fusion: 1x1 conv over bf16-hi [featBh[t], featFh[t]] (K=128) + bias
// + x. Weight hi/lo kept (AhBh + AlBh): final-output precision.
// ---------------------------------------------------------------------------
__global__ __launch_bounds__(128) void fusem_k(
    const ushort_t* __restrict__ featBh, const ushort_t* __restrict__ featFh,
    const float* __restrict__ x, const ushort_t* __restrict__ wfrag,
    const float* __restrict__ bias, float* __restrict__ out) {
    const int tid = threadIdx.x;
    const int lane = tid & 63;
    const int w = tid >> 6;
    const int h = blockIdx.x & 1;
    const int bseg = blockIdx.x >> 1;
    const int t = blockIdx.y;
    const int ot = h * 2 + w;
    const int xb = (bseg % 6) * 16;
    const int y = bseg / 6;
    const int n = lane & 15;
    const int quad = lane >> 4;

    __shared__ __align__(16) ushort_t ldsH[16 * 144];

    const int p = tid >> 3, cg = tid & 7;
    const int off = ((y * 96 + xb + p) * 64 + cg * 8);
#pragma unroll
    for (int i = 0; i < 2; ++i) {  // i=0: featB (ch 0-63), i=1: featF (64-127)
        const ushort_t* sv =
            (i == 0 ? featBh : featFh) + (size_t)t * FRAME;
        u16x8 a = *(const u16x8*)(sv + off);
        *(u16x8*)(ldsH + p * 144 + i * 64 + cg * 8) = a;
    }
    __syncthreads();

    f32x4 acc0, acc1;
#pragma unroll
    for (int r = 0; r < 4; ++r) { acc0[r] = 0.f; acc1[r] = 0.f; }
    const size_t hlOff = (size_t)4 * 4 * 512;
#pragma unroll
    for (int cc = 0; cc < 4; ++cc) {
        const ushort_t* ab = wfrag + (((size_t)cc * 4 + ot) * 64 + lane) * 8;
        bf16x8 Ah = *(const bf16x8*)ab;
        bf16x8 Al = *(const bf16x8*)(ab + hlOff);
        int lb = n * 144 + cc * 32 + quad * 8;
        bf16x8 Bh = *(const bf16x8*)(ldsH + lb);
        if (cc & 1) {
            acc1 = __builtin_amdgcn_mfma_f32_16x16x32_bf16(Ah, Bh, acc1, 0, 0, 0);
            acc1 = __builtin_amdgcn_mfma_f32_16x16x32_bf16(Al, Bh, acc1, 0, 0, 0);
        } else {
            acc0 = __builtin_amdgcn_mfma_f32_16x16x32_bf16(Ah, Bh, acc0, 0, 0, 0);
            acc0 = __builtin_amdgcn_mfma_f32_16x16x32_bf16(Al, Bh, acc0, 0, 0, 0);
        }
    }

    const int pidx = y * 96 + xb + n;
    const float* xt = x + (size_t)t * FRAME;
    float* od = out + (size_t)t * FRAME;
#pragma unroll
    for (int r = 0; r < 4; ++r) {
        int cout = ot * 16 + quad * 4 + r;
        size_t o2 = (size_t)cout * HW96 + pidx;
        od[o2] = acc0[r] + acc1[r] + bias[cout] + xt[o2];
    }
}

// ---------------------------------------------------------------------------
extern "C" void kernel_launch(void* const* d_in, const int* in_sizes, int n_in,
                              void* d_out, int out_size, void* d_ws,
                              size_t ws_size, hipStream_t stream) {
    const float* x = (const float*)d_in[0];
    auto gp = [&](int i) { return (const float*)d_in[i]; };

    struct DirP {
        const float *dw, *db, *ow1, *ob1, *ow2, *ob2, *ow3, *ob3, *ow4, *ob4,
            *bw1, *bb1, *bw2, *bb2;
    };
    DirP Pb{gp(1), gp(2), gp(3), gp(4), gp(5), gp(6), gp(7),
            gp(8), gp(9), gp(10), gp(11), gp(12), gp(13), gp(14)};
    DirP Pf{gp(15), gp(16), gp(17), gp(18), gp(19), gp(20), gp(21),
            gp(22), gp(23), gp(24), gp(25), gp(26), gp(27), gp(28)};
    const float* fus_w = gp(29);
    const float* fus_b = gp(30);

    // ---- workspace carve-up: all feature/intermediate bufs bf16-hi ushort --
    ushort_t* xh = (ushort_t*)d_ws;                       // 8 frames
    ushort_t* featBh = xh + (size_t)8 * FRAME;            // 8 frames
    ushort_t* featFh = featBh + (size_t)8 * FRAME;        // 8 frames
    ushort_t* hAh = featFh + (size_t)8 * FRAME;           // 1 frame
    ushort_t* hBh = hAh + FRAME;                          // 1 frame
    float* pacc = (float*)((((uintptr_t)(hBh + FRAME)) + 15) & ~(uintptr_t)15);
    ushort_t* fragp = (ushort_t*)(pacc + (size_t)2 * FRAME);

    auto falloc = [&](size_t nelem) {
        ushort_t* p = fragp;
        fragp += nelem;
        return p;
    };

    struct DirW { ushort_t *ow1, *ow2, *ow3, *ow4, *bw1, *bw2, *dw; int bw1KC; };
    FragJobs fj;
    int nf = 0;
    auto fjob = [&](const float* src, int O, int I, int OT, int KC) {
        ushort_t* dst = falloc((size_t)2 * 9 * KC * OT * 512);
        fj.j[nf++] = FragJob{src, dst, O, I, OT, KC, 0};
        return dst;
    };
    auto fjobd = [&](const float* src) {
        ushort_t* dst = falloc((size_t)2 * 36 * 4 * 512);
        fj.j[nf++] = FragJob{src, dst, 64, 128, 4, 36, 1};
        return dst;
    };
    DirW Wb, Wf;
    Wb.ow1 = fjob(Pb.ow1, 64, 192, 4, 6);
    Wb.ow2 = fjob(Pb.ow2, 64, 64, 4, 2);
    Wb.ow3 = fjob(Pb.ow3, 64, 64, 4, 2);
    Wb.ow4 = fjob(Pb.ow4, 432, 64, 28, 2);
    Wb.bw1 = fjob(Pb.bw1, 64, 128, 4, 4);
    Wb.bw1KC = 4;
    Wb.bw2 = fjob(Pb.bw2, 64, 64, 4, 2);
    Wb.dw = fjobd(Pb.dw);
    Wf.ow1 = fjob(Pf.ow1, 64, 192, 4, 6);
    Wf.ow2 = fjob(Pf.ow2, 64, 64, 4, 2);
    Wf.ow3 = fjob(Pf.ow3, 64, 64, 4, 2);
    Wf.ow4 = fjob(Pf.ow4, 432, 64, 28, 2);
    Wf.bw1 = fjob(Pf.bw1, 64, 192, 4, 6);
    Wf.bw1KC = 6;
    Wf.bw2 = fjob(Pf.bw2, 64, 64, 4, 2);
    Wf.dw = fjobd(Pf.dw);
    // fusion 1x1 weights (mode 2): O=64, I=128, OT=4, KC=4
    ushort_t* Wfus = falloc((size_t)2 * 4 * 4 * 512);
    fj.j[nf++] = FragJob{fus_w, Wfus, 64, 128, 4, 4, 2};
    frag_all_k<<<dim3(1008, 15), 256, 0, stream>>>(fj);

    pack_tr_k<<<dim3(144, 8), 256, 0, stream>>>(x, xh);

    auto convh = [&](const ushort_t* a, const ushort_t* b, const ushort_t* c2,
                     const ushort_t* frag, int KCfull, const float* bias,
                     ushort_t* out, int act) {
        const ushort_t* srcs[3] = {a, b, c2};
        const ushort_t* S[3] = {nullptr, nullptr, nullptr};
        int B[3] = {0, 0, 0};
        int ns = 0;
        for (int j = 0; j < 3; ++j)
            if (srcs[j]) {
                S[ns] = srcs[j];
                B[ns] = j * 2;
                ++ns;
            }
        convh_k<<<1152, 128, 0, stream>>>(S[0], S[1], S[2], B[0], B[1], B[2],
                                          ns, frag, KCfull, bias, out, act);
    };

    auto convb = [&](const ushort_t* a, const ushort_t* b, int withD,
                     const float* ddbias, const ushort_t* frag, int KCfull,
                     const float* bias, const float* add, const float* add2,
                     const float* abias, ushort_t* out, int act) {
        const ushort_t* S[2] = {nullptr, nullptr};
        int ns = 0;
        if (a) S[ns++] = a;
        if (b) S[ns++] = b;
        int dslot = -1;
        if (withD) { dslot = ns; ++ns; }
        convb_k<<<1152, 128, 0, stream>>>(S[0], S[1], ns, dslot, pacc, ddbias,
                                          frag, KCfull, bias, add, add2,
                                          abias, out, act);
    };

    for (int dir = 0; dir < 2; ++dir) {  // 0 = backward, 1 = forward
        const DirP& P = dir ? Pf : Pb;
        const DirW& W = dir ? Wf : Wb;
        ushort_t* feath = dir ? featFh : featBh;
        const ushort_t* prev1h = nullptr;
        const ushort_t* prev2h = nullptr;
        for (int i = 0; i < 8; ++i) {
            int idx = dir ? i : 7 - i;
            const ushort_t* curh = xh + (size_t)idx * FRAME;
            bool hasD = false;
            if (i > 0) {
                // offset/mask path: pure bf16-hi (convh)
                convh(prev1h, curh, prev2h, W.ow1, 6, P.ob1, hAh, 1);
                convh(hAh, nullptr, nullptr, W.ow2, 2, P.ob2, hBh, 1);
                convh(hBh, nullptr, nullptr, W.ow3, 2, P.ob3, hAh, 1);
                int ngr4 = (prev2h != nullptr) ? 4 : 2;
                dconv_fused_k<<<1152, 256, 0, stream>>>(
                    prev1h, prev2h, hAh, W.ow4, P.ob4, W.dw, ngr4, pacc);
                hasD = true;
            }
            ushort_t* dsth = feath + (size_t)idx * FRAME;
            // bw1: hi-only, D staged from interleaved pacc
            if (dir == 0) {
                convb(curh, nullptr, hasD ? 1 : 0, P.db, W.bw1, W.bw1KC,
                      P.bb1, nullptr, nullptr, nullptr, hBh, 1);
            } else {
                convb(curh, featBh + (size_t)idx * FRAME, hasD ? 1 : 0, P.db,
                      W.bw1, W.bw1KC, P.bb1, nullptr, nullptr, nullptr, hBh,
                      1);
            }
            // bw2: hi-only + interleaved pacc addsrc, writes feature hi shadow
            convb(hBh, nullptr, 0, nullptr, W.bw2, 2, P.bb2,
                  hasD ? pacc : nullptr, pacc + FRAME, P.db, dsth, 0);
            prev2h = prev1h;
            prev1h = dsth;
        }
    }

    fusem_k<<<dim3(1152, 8), 128, 0, stream>>>(featBh, featFh, x, Wfus,
                                               fus_b, (float*)d_out);
}